// Round 2
// baseline (540.757 us; speedup 1.0000x reference)
//
#include <hip/hip_runtime.h>
#include <hip/hip_bf16.h>

// Problem constants
#define T_TOKENS 4096      // B*S
#define DIM      1024
#define HID      4096
#define NE       8
#define CAP      4096      // max tokens per expert
#define SPLITS   4         // split-K factor for ffn2
#define KSP      (HID / SPLITS)   // 1024

typedef __attribute__((ext_vector_type(8))) short  bf16x8;
typedef __attribute__((ext_vector_type(4))) float  f32x4;
typedef __attribute__((ext_vector_type(4))) ushort u16x4;

__device__ static inline ushort f2bf(float f) {
    __hip_bfloat16 h = __float2bfloat16(f);
    return *(ushort*)&h;
}

// async global -> LDS, 16 bytes per lane. Global src is per-lane, LDS dest is
// wave-uniform base + lane*16 (linear). Swizzle is applied on the GLOBAL src.
__device__ static inline void gll16(const void* g, void* l) {
    __builtin_amdgcn_global_load_lds(
        (const __attribute__((address_space(1))) void*)g,
        (__attribute__((address_space(3))) void*)l,
        16, 0, 0);
}

// ---------------------------------------------------------------------------
// Gate: logits -> top2 -> softmax -> per-expert token lists; also x -> bf16.
// One wave per token.
// ---------------------------------------------------------------------------
__global__ __launch_bounds__(64) void gate_kernel(
    const float* __restrict__ x, const float* __restrict__ gw,
    const float* __restrict__ gb, __hip_bfloat16* __restrict__ xb,
    int* __restrict__ counts, int* __restrict__ tlist, float* __restrict__ plist)
{
    const int tok = blockIdx.x;
    const int l   = threadIdx.x;
    const float* xr = x + (size_t)tok * DIM;

    float part[NE];
#pragma unroll
    for (int e = 0; e < NE; e++) part[e] = 0.f;

#pragma unroll
    for (int i = 0; i < DIM / 64; i++) {
        int d = i * 64 + l;
        float xv = xr[d];
        xb[(size_t)tok * DIM + d] = __float2bfloat16(xv);
        const float4* g4 = (const float4*)(gw + (size_t)d * NE);
        float4 a = g4[0], b = g4[1];
        part[0] += xv * a.x; part[1] += xv * a.y;
        part[2] += xv * a.z; part[3] += xv * a.w;
        part[4] += xv * b.x; part[5] += xv * b.y;
        part[6] += xv * b.z; part[7] += xv * b.w;
    }
#pragma unroll
    for (int off = 32; off > 0; off >>= 1) {
#pragma unroll
        for (int e = 0; e < NE; e++) part[e] += __shfl_xor(part[e], off, 64);
    }
    if (l == 0) {
        float lg[NE];
#pragma unroll
        for (int e = 0; e < NE; e++) lg[e] = part[e] + gb[e];
        int i0 = 0;
#pragma unroll
        for (int e = 1; e < NE; e++) if (lg[e] > lg[i0]) i0 = e;   // lowest idx on tie
        int i1 = (i0 == 0) ? 1 : 0;
#pragma unroll
        for (int e = 0; e < NE; e++) if (e != i0 && lg[e] > lg[i1]) i1 = e;
        float t  = expf(lg[i1] - lg[i0]);     // softmax over the 2 picked logits
        float p0 = 1.f / (1.f + t);
        float p1 = t / (1.f + t);
        int pos0 = atomicAdd(&counts[i0], 1);
        tlist[i0 * CAP + pos0] = tok; plist[i0 * CAP + pos0] = p0;
        int pos1 = atomicAdd(&counts[i1], 1);
        tlist[i1 * CAP + pos1] = tok; plist[i1 * CAP + pos1] = p1;
    }
}

__global__ void finalize_kernel(const int* __restrict__ counts, int* __restrict__ base)
{
    if (threadIdx.x == 0) {
        int acc = 0;
        for (int e = 0; e < NE; e++) { base[e] = acc; acc += counts[e]; }
        base[NE] = acc;
    }
}

// ---------------------------------------------------------------------------
// Transpose + f32->bf16 convert:  in [E][K][N] f32  ->  out [E][N][K] bf16
// 64x64 tile: float4 reads, ushort4 (8B) fully-coalesced writes.
// ---------------------------------------------------------------------------
__global__ __launch_bounds__(256) void transpose_cvt64(
    const float* __restrict__ in, __hip_bfloat16* __restrict__ outp, int K, int N)
{
    __shared__ ushort tile[64][68];
    const int e  = blockIdx.z;
    const float* src = in + (size_t)e * K * N;
    ushort* dst = (ushort*)outp + (size_t)e * K * N;
    const int k0 = blockIdx.y * 64, n0 = blockIdx.x * 64;
    const int tid = threadIdx.x;

    const int rn4 = (tid & 15) * 4;   // n offset (float4)
    const int rk  = tid >> 4;         // 16 k rows per pass
#pragma unroll
    for (int p = 0; p < 4; p++) {
        int k = rk + p * 16;
        float4 v = *(const float4*)&src[(size_t)(k0 + k) * N + n0 + rn4];
        tile[k][rn4 + 0] = f2bf(v.x);
        tile[k][rn4 + 1] = f2bf(v.y);
        tile[k][rn4 + 2] = f2bf(v.z);
        tile[k][rn4 + 3] = f2bf(v.w);
    }
    __syncthreads();
    const int wk4 = (tid & 15) * 4;   // k offset (ushort4)
    const int wn  = tid >> 4;         // 16 n rows per pass
#pragma unroll
    for (int p = 0; p < 4; p++) {
        int n = wn + p * 16;
        u16x4 u;
        u[0] = tile[wk4 + 0][n];
        u[1] = tile[wk4 + 1][n];
        u[2] = tile[wk4 + 2][n];
        u[3] = tile[wk4 + 3][n];
        *(u16x4*)&dst[(size_t)(n0 + n) * K + k0 + wk4] = u;
    }
}

// ---------------------------------------------------------------------------
// Grouped GEMM pass 1:  H = gelu( gather(xb) @ w1t^T + b1 )   (per expert)
// 128x128 tile, BK=32, 4 waves (2x2), 16x16x32 bf16 MFMA, double-buffered LDS.
// LDS layout [128 rows][4 chunks of 8 bf16], chunk xor-swizzled by (row>>1)&3.
// ---------------------------------------------------------------------------
__global__ __launch_bounds__(256, 3) void ffn1_kernel(
    const __hip_bfloat16* __restrict__ xb, const __hip_bfloat16* __restrict__ w1t,
    const float* __restrict__ b1, const int* __restrict__ counts,
    const int* __restrict__ base, const int* __restrict__ tlist,
    __hip_bfloat16* __restrict__ H)
{
    const int e  = blockIdx.z;
    const int ne = counts[e];
    const int rb = blockIdx.y, cb = blockIdx.x;
    if (rb * 128 >= ne) return;

    __shared__ __align__(16) ushort ldsA[2][4096];
    __shared__ __align__(16) ushort ldsB[2][4096];

    const int t = threadIdx.x;
    const int l = t & 63, w = t >> 6;
    const int wr = w >> 1, wc = w & 1;

    const int slot0 = w * 128 + l;
    const int slot1 = w * 128 + 64 + l;
    const int row0 = slot0 >> 2, row1 = slot1 >> 2;
    const int ch0 = ((slot0 & 3) ^ ((row0 >> 1) & 3)) * 8;
    const int ch1 = ((slot1 & 3) ^ ((row1 >> 1) & 3)) * 8;
    const int lo0 = w * 1024;
    const int lo1 = w * 1024 + 512;

    const int r0g = rb * 128 + row0, r1g = rb * 128 + row1;
    const int tok0 = tlist[e * CAP + (r0g < ne ? r0g : 0)];
    const int tok1 = tlist[e * CAP + (r1g < ne ? r1g : 0)];
    const ushort* aS0 = (const ushort*)xb + (size_t)tok0 * DIM + ch0;
    const ushort* aS1 = (const ushort*)xb + (size_t)tok1 * DIM + ch1;
    const ushort* bS0 = (const ushort*)w1t + ((size_t)e * HID + cb * 128 + row0) * DIM + ch0;
    const ushort* bS1 = (const ushort*)w1t + ((size_t)e * HID + cb * 128 + row1) * DIM + ch1;

    f32x4 acc[4][4];
#pragma unroll
    for (int i = 0; i < 4; i++)
#pragma unroll
        for (int j = 0; j < 4; j++) acc[i][j] = (f32x4){0.f, 0.f, 0.f, 0.f};

    const int lm = l & 15, lgp = l >> 4;
    const int rch = (lgp ^ ((lm >> 1) & 3)) * 8;

    gll16(aS0, &ldsA[0][lo0]); gll16(aS1, &ldsA[0][lo1]);
    gll16(bS0, &ldsB[0][lo0]); gll16(bS1, &ldsB[0][lo1]);

    int cur = 0;
    const int NK = DIM / 32;
    for (int ks = 0; ks < NK; ks++) {
        __syncthreads();
        if (ks + 1 < NK) {
            const int ko = (ks + 1) * 32;
            gll16(aS0 + ko, &ldsA[cur ^ 1][lo0]); gll16(aS1 + ko, &ldsA[cur ^ 1][lo1]);
            gll16(bS0 + ko, &ldsB[cur ^ 1][lo0]); gll16(bS1 + ko, &ldsB[cur ^ 1][lo1]);
        }
        bf16x8 af[4], bfr[4];
#pragma unroll
        for (int i = 0; i < 4; i++) {
            int row = wr * 64 + i * 16 + lm;
            af[i] = *(const bf16x8*)&ldsA[cur][row * 32 + rch];
        }
#pragma unroll
        for (int j = 0; j < 4; j++) {
            int row = wc * 64 + j * 16 + lm;
            bfr[j] = *(const bf16x8*)&ldsB[cur][row * 32 + rch];
        }
#pragma unroll
        for (int i = 0; i < 4; i++)
#pragma unroll
            for (int j = 0; j < 4; j++)
                acc[i][j] = __builtin_amdgcn_mfma_f32_16x16x32_bf16(af[i], bfr[j], acc[i][j], 0, 0, 0);
        cur ^= 1;
    }

    const int hb = base[e];
#pragma unroll
    for (int i = 0; i < 4; i++) {
#pragma unroll
        for (int jj = 0; jj < 4; jj++) {
            int r = rb * 128 + wr * 64 + i * 16 + lgp * 4 + jj;
            if (r < ne) {
                size_t hrow = (size_t)(hb + r) * HID;
#pragma unroll
                for (int j = 0; j < 4; j++) {
                    int col = cb * 128 + wc * 64 + j * 16 + lm;
                    float v = acc[i][j][jj] + b1[e * HID + col];
                    v = 0.5f * v * (1.0f + erff(v * 0.70710678118654752f));  // exact GELU
                    H[hrow + col] = __float2bfloat16(v);
                }
            }
        }
    }
}

// ---------------------------------------------------------------------------
// Grouped GEMM pass 2 (split-K):  out[token] += prob * ( H @ w2t^T + b2 )
// blockIdx.y encodes (rb, split). Each split covers KSP of HID; bias added
// only by split 0. Out accumulation via f32 atomics.
// ---------------------------------------------------------------------------
__global__ __launch_bounds__(256, 3) void ffn2_kernel(
    const __hip_bfloat16* __restrict__ H, const __hip_bfloat16* __restrict__ w2t,
    const float* __restrict__ b2, const int* __restrict__ counts,
    const int* __restrict__ base, const int* __restrict__ tlist,
    const float* __restrict__ plist, float* __restrict__ out)
{
    const int e  = blockIdx.z;
    const int ne = counts[e];
    const int rb = blockIdx.y >> 2;       // / SPLITS
    const int sp = blockIdx.y & 3;        // % SPLITS
    const int cb = blockIdx.x;
    if (rb * 128 >= ne) return;

    __shared__ __align__(16) ushort ldsA[2][4096];
    __shared__ __align__(16) ushort ldsB[2][4096];

    const int t = threadIdx.x;
    const int l = t & 63, w = t >> 6;
    const int wr = w >> 1, wc = w & 1;

    const int slot0 = w * 128 + l;
    const int slot1 = w * 128 + 64 + l;
    const int row0 = slot0 >> 2, row1 = slot1 >> 2;
    const int ch0 = ((slot0 & 3) ^ ((row0 >> 1) & 3)) * 8;
    const int ch1 = ((slot1 & 3) ^ ((row1 >> 1) & 3)) * 8;
    const int lo0 = w * 1024;
    const int lo1 = w * 1024 + 512;

    const int hb = base[e];
    const int r0g = rb * 128 + row0, r1g = rb * 128 + row1;
    const int hr0 = hb + (r0g < ne ? r0g : ne - 1);
    const int hr1 = hb + (r1g < ne ? r1g : ne - 1);
    const size_t ko0 = (size_t)sp * KSP;
    const ushort* aS0 = (const ushort*)H + (size_t)hr0 * HID + ko0 + ch0;
    const ushort* aS1 = (const ushort*)H + (size_t)hr1 * HID + ko0 + ch1;
    const ushort* bS0 = (const ushort*)w2t + ((size_t)e * DIM + cb * 128 + row0) * HID + ko0 + ch0;
    const ushort* bS1 = (const ushort*)w2t + ((size_t)e * DIM + cb * 128 + row1) * HID + ko0 + ch1;

    f32x4 acc[4][4];
#pragma unroll
    for (int i = 0; i < 4; i++)
#pragma unroll
        for (int j = 0; j < 4; j++) acc[i][j] = (f32x4){0.f, 0.f, 0.f, 0.f};

    const int lm = l & 15, lgp = l >> 4;
    const int rch = (lgp ^ ((lm >> 1) & 3)) * 8;

    gll16(aS0, &ldsA[0][lo0]); gll16(aS1, &ldsA[0][lo1]);
    gll16(bS0, &ldsB[0][lo0]); gll16(bS1, &ldsB[0][lo1]);

    int cur = 0;
    const int NK = KSP / 32;
    for (int ks = 0; ks < NK; ks++) {
        __syncthreads();
        if (ks + 1 < NK) {
            const int ko = (ks + 1) * 32;
            gll16(aS0 + ko, &ldsA[cur ^ 1][lo0]); gll16(aS1 + ko, &ldsA[cur ^ 1][lo1]);
            gll16(bS0 + ko, &ldsB[cur ^ 1][lo0]); gll16(bS1 + ko, &ldsB[cur ^ 1][lo1]);
        }
        bf16x8 af[4], bfr[4];
#pragma unroll
        for (int i = 0; i < 4; i++) {
            int row = wr * 64 + i * 16 + lm;
            af[i] = *(const bf16x8*)&ldsA[cur][row * 32 + rch];
        }
#pragma unroll
        for (int j = 0; j < 4; j++) {
            int row = wc * 64 + j * 16 + lm;
            bfr[j] = *(const bf16x8*)&ldsB[cur][row * 32 + rch];
        }
#pragma unroll
        for (int i = 0; i < 4; i++)
#pragma unroll
            for (int j = 0; j < 4; j++)
                acc[i][j] = __builtin_amdgcn_mfma_f32_16x16x32_bf16(af[i], bfr[j], acc[i][j], 0, 0, 0);
        cur ^= 1;
    }

#pragma unroll
    for (int i = 0; i < 4; i++) {
#pragma unroll
        for (int jj = 0; jj < 4; jj++) {
            int r = rb * 128 + wr * 64 + i * 16 + lgp * 4 + jj;
            if (r < ne) {
                int tok  = tlist[e * CAP + r];
                float p  = plist[e * CAP + r];
                float* orow = out + (size_t)tok * DIM;
#pragma unroll
                for (int j = 0; j < 4; j++) {
                    int col = cb * 128 + wc * 64 + j * 16 + lm;
                    float v = acc[i][j][jj];
                    if (sp == 0) v += b2[e * DIM + col];
                    unsafeAtomicAdd(&orow[col], v * p);
                }
            }
        }
    }
}

// ---------------------------------------------------------------------------
extern "C" void kernel_launch(void* const* d_in, const int* in_sizes, int n_in,
                              void* d_out, int out_size, void* d_ws, size_t ws_size,
                              hipStream_t stream)
{
    const float* x  = (const float*)d_in[0];
    const float* gw = (const float*)d_in[1];
    const float* gb = (const float*)d_in[2];
    const float* w1 = (const float*)d_in[3];
    const float* b1 = (const float*)d_in[4];
    const float* w2 = (const float*)d_in[5];
    const float* b2 = (const float*)d_in[6];
    float* out = (float*)d_out;

    // workspace carve (bytes)
    char* ws = (char*)d_ws;
    __hip_bfloat16* w1t = (__hip_bfloat16*)(ws);                    // 67108864
    __hip_bfloat16* w2t = (__hip_bfloat16*)(ws + 67108864);         // 67108864
    __hip_bfloat16* Hb  = (__hip_bfloat16*)(ws + 134217728);        // 67108864
    __hip_bfloat16* xb  = (__hip_bfloat16*)(ws + 201326592);        // 8388608
    int*   tlist  = (int*)  (ws + 209715200);                       // 131072
    float* plist  = (float*)(ws + 209846272);                       // 131072
    int*   counts = (int*)  (ws + 209977344);                       // 64
    int*   basep  = (int*)  (ws + 209977408);                       // 64

    hipMemsetAsync(out, 0, (size_t)T_TOKENS * DIM * sizeof(float), stream);
    hipMemsetAsync(counts, 0, 64, stream);

    gate_kernel<<<T_TOKENS, 64, 0, stream>>>(x, gw, gb, xb, counts, tlist, plist);
    finalize_kernel<<<1, 64, 0, stream>>>(counts, basep);

    transpose_cvt64<<<dim3(HID / 64, DIM / 64, NE), 256, 0, stream>>>(w1, w1t, DIM, HID);
    transpose_cvt64<<<dim3(DIM / 64, HID / 64, NE), 256, 0, stream>>>(w2, w2t, HID, DIM);

    ffn1_kernel<<<dim3(HID / 128, CAP / 128, NE), 256, 0, stream>>>(
        xb, w1t, b1, counts, basep, tlist, Hb);
    ffn2_kernel<<<dim3(DIM / 128, (CAP / 128) * SPLITS, NE), 256, 0, stream>>>(
        Hb, w2t, b2, counts, basep, tlist, plist, out);
}

// Round 3
// 503.616 us; speedup vs baseline: 1.0737x; 1.0737x over previous
//
#include <hip/hip_runtime.h>
#include <hip/hip_bf16.h>

// Problem constants
#define T_TOKENS 4096      // B*S
#define DIM      1024
#define HID      4096
#define NE       8
#define CAP      4096      // max tokens per expert
#define SPLITS   2         // split-K factor for ffn2
#define KSP      (HID / SPLITS)   // 2048

typedef __attribute__((ext_vector_type(8))) short  bf16x8;
typedef __attribute__((ext_vector_type(4))) float  f32x4;
typedef __attribute__((ext_vector_type(4))) ushort u16x4;

__device__ static inline ushort f2bf(float f) {
    __hip_bfloat16 h = __float2bfloat16(f);
    return *(ushort*)&h;
}

// async global -> LDS, 16 bytes per lane. Global src is per-lane, LDS dest is
// wave-uniform base + lane*16 (linear). Swizzle is applied on the GLOBAL src.
__device__ static inline void gll16(const void* g, void* l) {
    __builtin_amdgcn_global_load_lds(
        (const __attribute__((address_space(1))) void*)g,
        (__attribute__((address_space(3))) void*)l,
        16, 0, 0);
}

// ---------------------------------------------------------------------------
// Gate: logits -> top2 -> softmax -> per-expert token lists; also x -> bf16.
// ---------------------------------------------------------------------------
__global__ __launch_bounds__(64) void gate_kernel(
    const float* __restrict__ x, const float* __restrict__ gw,
    const float* __restrict__ gb, __hip_bfloat16* __restrict__ xb,
    int* __restrict__ counts, int* __restrict__ tlist, float* __restrict__ plist)
{
    const int tok = blockIdx.x;
    const int l   = threadIdx.x;
    const float* xr = x + (size_t)tok * DIM;

    float part[NE];
#pragma unroll
    for (int e = 0; e < NE; e++) part[e] = 0.f;

#pragma unroll
    for (int i = 0; i < DIM / 64; i++) {
        int d = i * 64 + l;
        float xv = xr[d];
        xb[(size_t)tok * DIM + d] = __float2bfloat16(xv);
        const float4* g4 = (const float4*)(gw + (size_t)d * NE);
        float4 a = g4[0], b = g4[1];
        part[0] += xv * a.x; part[1] += xv * a.y;
        part[2] += xv * a.z; part[3] += xv * a.w;
        part[4] += xv * b.x; part[5] += xv * b.y;
        part[6] += xv * b.z; part[7] += xv * b.w;
    }
#pragma unroll
    for (int off = 32; off > 0; off >>= 1) {
#pragma unroll
        for (int e = 0; e < NE; e++) part[e] += __shfl_xor(part[e], off, 64);
    }
    if (l == 0) {
        float lg[NE];
#pragma unroll
        for (int e = 0; e < NE; e++) lg[e] = part[e] + gb[e];
        int i0 = 0;
#pragma unroll
        for (int e = 1; e < NE; e++) if (lg[e] > lg[i0]) i0 = e;   // lowest idx on tie
        int i1 = (i0 == 0) ? 1 : 0;
#pragma unroll
        for (int e = 0; e < NE; e++) if (e != i0 && lg[e] > lg[i1]) i1 = e;
        float t  = expf(lg[i1] - lg[i0]);
        float p0 = 1.f / (1.f + t);
        float p1 = t / (1.f + t);
        int pos0 = atomicAdd(&counts[i0], 1);
        tlist[i0 * CAP + pos0] = tok; plist[i0 * CAP + pos0] = p0;
        int pos1 = atomicAdd(&counts[i1], 1);
        tlist[i1 * CAP + pos1] = tok; plist[i1 * CAP + pos1] = p1;
    }
}

__global__ void finalize_kernel(const int* __restrict__ counts, int* __restrict__ base)
{
    if (threadIdx.x == 0) {
        int acc = 0;
        for (int e = 0; e < NE; e++) { base[e] = acc; acc += counts[e]; }
        base[NE] = acc;
    }
}

// ---------------------------------------------------------------------------
// Transpose + f32->bf16 convert:  in [E][K][N] f32  ->  out [E][N][K] bf16
// ---------------------------------------------------------------------------
__global__ __launch_bounds__(256) void transpose_cvt64(
    const float* __restrict__ in, __hip_bfloat16* __restrict__ outp, int K, int N)
{
    __shared__ ushort tile[64][68];
    const int e  = blockIdx.z;
    const float* src = in + (size_t)e * K * N;
    ushort* dst = (ushort*)outp + (size_t)e * K * N;
    const int k0 = blockIdx.y * 64, n0 = blockIdx.x * 64;
    const int tid = threadIdx.x;

    const int rn4 = (tid & 15) * 4;
    const int rk  = tid >> 4;
#pragma unroll
    for (int p = 0; p < 4; p++) {
        int k = rk + p * 16;
        float4 v = *(const float4*)&src[(size_t)(k0 + k) * N + n0 + rn4];
        tile[k][rn4 + 0] = f2bf(v.x);
        tile[k][rn4 + 1] = f2bf(v.y);
        tile[k][rn4 + 2] = f2bf(v.z);
        tile[k][rn4 + 3] = f2bf(v.w);
    }
    __syncthreads();
    const int wk4 = (tid & 15) * 4;
    const int wn  = tid >> 4;
#pragma unroll
    for (int p = 0; p < 4; p++) {
        int n = wn + p * 16;
        u16x4 u;
        u[0] = tile[wk4 + 0][n];
        u[1] = tile[wk4 + 1][n];
        u[2] = tile[wk4 + 2][n];
        u[3] = tile[wk4 + 3][n];
        *(u16x4*)&dst[(size_t)(n0 + n) * K + k0 + wk4] = u;
    }
}

// ---------------------------------------------------------------------------
// Grouped GEMM pass 1:  H = gelu( gather(xb) @ w1t^T + b1 )   (per expert)
// 128x128 tile, BK=32, 4 waves, 16x16x32 bf16 MFMA.
// 3-deep LDS buffers + counted vmcnt: 2 tiles always in flight, so each
// tile's loads get ~2 k-steps of latency slack (T4 counted-vmcnt).
// Per wave per tile: exactly 4 gll16 -> steady-state outstanding = 8;
// vmcnt(4) lands the current tile, last step drains with vmcnt(0).
// ---------------------------------------------------------------------------
__global__ __launch_bounds__(256, 3) void ffn1_kernel(
    const __hip_bfloat16* __restrict__ xb, const __hip_bfloat16* __restrict__ w1t,
    const float* __restrict__ b1, const int* __restrict__ counts,
    const int* __restrict__ base, const int* __restrict__ tlist,
    __hip_bfloat16* __restrict__ H)
{
    const int e  = blockIdx.z;
    const int ne = counts[e];
    const int rb = blockIdx.y, cb = blockIdx.x;
    if (rb * 128 >= ne) return;

    __shared__ __align__(16) ushort ldsA[3][4096];
    __shared__ __align__(16) ushort ldsB[3][4096];

    const int t = threadIdx.x;
    const int l = t & 63, w = t >> 6;
    const int wr = w >> 1, wc = w & 1;

    const int slot0 = w * 128 + l;
    const int slot1 = w * 128 + 64 + l;
    const int row0 = slot0 >> 2, row1 = slot1 >> 2;
    const int ch0 = ((slot0 & 3) ^ ((row0 >> 1) & 3)) * 8;
    const int ch1 = ((slot1 & 3) ^ ((row1 >> 1) & 3)) * 8;
    const int lo0 = w * 1024;
    const int lo1 = w * 1024 + 512;

    const int r0g = rb * 128 + row0, r1g = rb * 128 + row1;
    const int tok0 = tlist[e * CAP + (r0g < ne ? r0g : 0)];
    const int tok1 = tlist[e * CAP + (r1g < ne ? r1g : 0)];
    const ushort* aS0 = (const ushort*)xb + (size_t)tok0 * DIM + ch0;
    const ushort* aS1 = (const ushort*)xb + (size_t)tok1 * DIM + ch1;
    const ushort* bS0 = (const ushort*)w1t + ((size_t)e * HID + cb * 128 + row0) * DIM + ch0;
    const ushort* bS1 = (const ushort*)w1t + ((size_t)e * HID + cb * 128 + row1) * DIM + ch1;

    f32x4 acc[4][4];
#pragma unroll
    for (int i = 0; i < 4; i++)
#pragma unroll
        for (int j = 0; j < 4; j++) acc[i][j] = (f32x4){0.f, 0.f, 0.f, 0.f};

    const int lm = l & 15, lgp = l >> 4;
    const int rch = (lgp ^ ((lm >> 1) & 3)) * 8;

    const int NK = DIM / 32;
    // prologue: tiles 0 and 1 in flight
    gll16(aS0, &ldsA[0][lo0]); gll16(aS1, &ldsA[0][lo1]);
    gll16(bS0, &ldsB[0][lo0]); gll16(bS1, &ldsB[0][lo1]);
    gll16(aS0 + 32, &ldsA[1][lo0]); gll16(aS1 + 32, &ldsA[1][lo1]);
    gll16(bS0 + 32, &ldsB[1][lo0]); gll16(bS1 + 32, &ldsB[1][lo1]);

    int rbuf = 0, wbuf = 2;
#pragma unroll 1
    for (int ks = 0; ks < NK; ks++) {
        if (ks < NK - 1) { asm volatile("s_waitcnt vmcnt(4)" ::: "memory"); }
        else             { asm volatile("s_waitcnt vmcnt(0)" ::: "memory"); }
        __builtin_amdgcn_s_barrier();
        if (ks + 2 < NK) {
            const int ko = (ks + 2) * 32;
            gll16(aS0 + ko, &ldsA[wbuf][lo0]); gll16(aS1 + ko, &ldsA[wbuf][lo1]);
            gll16(bS0 + ko, &ldsB[wbuf][lo0]); gll16(bS1 + ko, &ldsB[wbuf][lo1]);
        }
        const ushort* pA = &ldsA[rbuf][0];
        const ushort* pB = &ldsB[rbuf][0];
        bf16x8 af[4], bfr[4];
#pragma unroll
        for (int i = 0; i < 4; i++) {
            int row = wr * 64 + i * 16 + lm;
            af[i] = *(const bf16x8*)&pA[row * 32 + rch];
        }
#pragma unroll
        for (int j = 0; j < 4; j++) {
            int row = wc * 64 + j * 16 + lm;
            bfr[j] = *(const bf16x8*)&pB[row * 32 + rch];
        }
#pragma unroll
        for (int i = 0; i < 4; i++)
#pragma unroll
            for (int j = 0; j < 4; j++)
                acc[i][j] = __builtin_amdgcn_mfma_f32_16x16x32_bf16(af[i], bfr[j], acc[i][j], 0, 0, 0);
        rbuf = (rbuf == 2) ? 0 : rbuf + 1;
        wbuf = (wbuf == 2) ? 0 : wbuf + 1;
    }

    const int hb = base[e];
#pragma unroll
    for (int i = 0; i < 4; i++) {
#pragma unroll
        for (int jj = 0; jj < 4; jj++) {
            int r = rb * 128 + wr * 64 + i * 16 + lgp * 4 + jj;
            if (r < ne) {
                size_t hrow = (size_t)(hb + r) * HID;
#pragma unroll
                for (int j = 0; j < 4; j++) {
                    int col = cb * 128 + wc * 64 + j * 16 + lm;
                    float v = acc[i][j][jj] + b1[e * HID + col];
                    v = 0.5f * v * (1.0f + erff(v * 0.70710678118654752f));  // exact GELU
                    H[hrow + col] = __float2bfloat16(v);
                }
            }
        }
    }
}

// ---------------------------------------------------------------------------
// Grouped GEMM pass 2 (split-K=2):  out[token] += prob * ( H @ w2t^T + b2 )
// Same 3-deep counted-vmcnt pipeline. Bias added only by split 0.
// ---------------------------------------------------------------------------
__global__ __launch_bounds__(256, 3) void ffn2_kernel(
    const __hip_bfloat16* __restrict__ H, const __hip_bfloat16* __restrict__ w2t,
    const float* __restrict__ b2, const int* __restrict__ counts,
    const int* __restrict__ base, const int* __restrict__ tlist,
    const float* __restrict__ plist, float* __restrict__ out)
{
    const int e  = blockIdx.z;
    const int ne = counts[e];
    const int rb = blockIdx.y >> 1;       // / SPLITS
    const int sp = blockIdx.y & 1;        // % SPLITS
    const int cb = blockIdx.x;
    if (rb * 128 >= ne) return;

    __shared__ __align__(16) ushort ldsA[3][4096];
    __shared__ __align__(16) ushort ldsB[3][4096];

    const int t = threadIdx.x;
    const int l = t & 63, w = t >> 6;
    const int wr = w >> 1, wc = w & 1;

    const int slot0 = w * 128 + l;
    const int slot1 = w * 128 + 64 + l;
    const int row0 = slot0 >> 2, row1 = slot1 >> 2;
    const int ch0 = ((slot0 & 3) ^ ((row0 >> 1) & 3)) * 8;
    const int ch1 = ((slot1 & 3) ^ ((row1 >> 1) & 3)) * 8;
    const int lo0 = w * 1024;
    const int lo1 = w * 1024 + 512;

    const int hb = base[e];
    const int r0g = rb * 128 + row0, r1g = rb * 128 + row1;
    const int hr0 = hb + (r0g < ne ? r0g : ne - 1);
    const int hr1 = hb + (r1g < ne ? r1g : ne - 1);
    const size_t ko0 = (size_t)sp * KSP;
    const ushort* aS0 = (const ushort*)H + (size_t)hr0 * HID + ko0 + ch0;
    const ushort* aS1 = (const ushort*)H + (size_t)hr1 * HID + ko0 + ch1;
    const ushort* bS0 = (const ushort*)w2t + ((size_t)e * DIM + cb * 128 + row0) * HID + ko0 + ch0;
    const ushort* bS1 = (const ushort*)w2t + ((size_t)e * DIM + cb * 128 + row1) * HID + ko0 + ch1;

    f32x4 acc[4][4];
#pragma unroll
    for (int i = 0; i < 4; i++)
#pragma unroll
        for (int j = 0; j < 4; j++) acc[i][j] = (f32x4){0.f, 0.f, 0.f, 0.f};

    const int lm = l & 15, lgp = l >> 4;
    const int rch = (lgp ^ ((lm >> 1) & 3)) * 8;

    const int NK = KSP / 32;
    gll16(aS0, &ldsA[0][lo0]); gll16(aS1, &ldsA[0][lo1]);
    gll16(bS0, &ldsB[0][lo0]); gll16(bS1, &ldsB[0][lo1]);
    gll16(aS0 + 32, &ldsA[1][lo0]); gll16(aS1 + 32, &ldsA[1][lo1]);
    gll16(bS0 + 32, &ldsB[1][lo0]); gll16(bS1 + 32, &ldsB[1][lo1]);

    int rbuf = 0, wbuf = 2;
#pragma unroll 1
    for (int ks = 0; ks < NK; ks++) {
        if (ks < NK - 1) { asm volatile("s_waitcnt vmcnt(4)" ::: "memory"); }
        else             { asm volatile("s_waitcnt vmcnt(0)" ::: "memory"); }
        __builtin_amdgcn_s_barrier();
        if (ks + 2 < NK) {
            const int ko = (ks + 2) * 32;
            gll16(aS0 + ko, &ldsA[wbuf][lo0]); gll16(aS1 + ko, &ldsA[wbuf][lo1]);
            gll16(bS0 + ko, &ldsB[wbuf][lo0]); gll16(bS1 + ko, &ldsB[wbuf][lo1]);
        }
        const ushort* pA = &ldsA[rbuf][0];
        const ushort* pB = &ldsB[rbuf][0];
        bf16x8 af[4], bfr[4];
#pragma unroll
        for (int i = 0; i < 4; i++) {
            int row = wr * 64 + i * 16 + lm;
            af[i] = *(const bf16x8*)&pA[row * 32 + rch];
        }
#pragma unroll
        for (int j = 0; j < 4; j++) {
            int row = wc * 64 + j * 16 + lm;
            bfr[j] = *(const bf16x8*)&pB[row * 32 + rch];
        }
#pragma unroll
        for (int i = 0; i < 4; i++)
#pragma unroll
            for (int j = 0; j < 4; j++)
                acc[i][j] = __builtin_amdgcn_mfma_f32_16x16x32_bf16(af[i], bfr[j], acc[i][j], 0, 0, 0);
        rbuf = (rbuf == 2) ? 0 : rbuf + 1;
        wbuf = (wbuf == 2) ? 0 : wbuf + 1;
    }

#pragma unroll
    for (int i = 0; i < 4; i++) {
#pragma unroll
        for (int jj = 0; jj < 4; jj++) {
            int r = rb * 128 + wr * 64 + i * 16 + lgp * 4 + jj;
            if (r < ne) {
                int tok  = tlist[e * CAP + r];
                float p  = plist[e * CAP + r];
                float* orow = out + (size_t)tok * DIM;
#pragma unroll
                for (int j = 0; j < 4; j++) {
                    int col = cb * 128 + wc * 64 + j * 16 + lm;
                    float v = acc[i][j][jj];
                    if (sp == 0) v += b2[e * DIM + col];
                    unsafeAtomicAdd(&orow[col], v * p);
                }
            }
        }
    }
}

// ---------------------------------------------------------------------------
extern "C" void kernel_launch(void* const* d_in, const int* in_sizes, int n_in,
                              void* d_out, int out_size, void* d_ws, size_t ws_size,
                              hipStream_t stream)
{
    const float* x  = (const float*)d_in[0];
    const float* gw = (const float*)d_in[1];
    const float* gb = (const float*)d_in[2];
    const float* w1 = (const float*)d_in[3];
    const float* b1 = (const float*)d_in[4];
    const float* w2 = (const float*)d_in[5];
    const float* b2 = (const float*)d_in[6];
    float* out = (float*)d_out;

    // workspace carve (bytes)
    char* ws = (char*)d_ws;
    __hip_bfloat16* w1t = (__hip_bfloat16*)(ws);                    // 67108864
    __hip_bfloat16* w2t = (__hip_bfloat16*)(ws + 67108864);         // 67108864
    __hip_bfloat16* Hb  = (__hip_bfloat16*)(ws + 134217728);        // 67108864
    __hip_bfloat16* xb  = (__hip_bfloat16*)(ws + 201326592);        // 8388608
    int*   tlist  = (int*)  (ws + 209715200);                       // 131072
    float* plist  = (float*)(ws + 209846272);                       // 131072
    int*   counts = (int*)  (ws + 209977344);                       // 64
    int*   basep  = (int*)  (ws + 209977408);                       // 64

    hipMemsetAsync(out, 0, (size_t)T_TOKENS * DIM * sizeof(float), stream);
    hipMemsetAsync(counts, 0, 64, stream);

    gate_kernel<<<T_TOKENS, 64, 0, stream>>>(x, gw, gb, xb, counts, tlist, plist);
    finalize_kernel<<<1, 64, 0, stream>>>(counts, basep);

    transpose_cvt64<<<dim3(HID / 64, DIM / 64, NE), 256, 0, stream>>>(w1, w1t, DIM, HID);
    transpose_cvt64<<<dim3(DIM / 64, HID / 64, NE), 256, 0, stream>>>(w2, w2t, HID, DIM);

    ffn1_kernel<<<dim3(HID / 128, CAP / 128, NE), 256, 0, stream>>>(
        xb, w1t, b1, counts, basep, tlist, Hb);
    ffn2_kernel<<<dim3(DIM / 128, (CAP / 128) * SPLITS, NE), 256, 0, stream>>>(
        Hb, w2t, b2, counts, basep, tlist, plist, out);
}